// Round 7
// baseline (59.677 us; speedup 1.0000x reference)
//
#include <hip/hip_runtime.h>
#include <hip/hip_bf16.h>
#include <stdint.h>

// out[b,o,p] = sum_{r,c} mat0[b,c,p] * mat1[o,c,r]*Alpha[r] * mask[r,p]
// GEMM: M=256 (o), N=32768 (n=b*4096+p), K=2048 (k=c*8+r).
// A[o,k] = mat1[o,c,r]*Alpha[r]  (prepped bf16 in d_ws, layout [c][o][r])
// B[k,n] = mat0[b,c,p]*mask[r,p] synthesized IN REGISTERS per lane.
// Round 7: R6 + 4-round-deep mat0 (P) prefetch ring. R6's stall was the
// P stream: in-place reload gave ~3 kq-phases (~440 cyc) of cover vs
// ~900 cyc HBM/L3 latency -> every round exposed ~600 cyc. P ring is
// 4 regs/round so depth-4 costs only 12 extra VGPRs. af (L2-resident)
// keeps the 3-phase in-place reload. All indices static (rule #20).

typedef __attribute__((ext_vector_type(8)))  short short8;
typedef __attribute__((ext_vector_type(16))) float f32x16;

#define C_IN  256
#define HW_   4096
#define NRND  32    // K rounds of 64 (8 c-planes per round)

__device__ __forceinline__ short f2bf(float x) {
  union { __hip_bfloat16 h; short s; } u;
  u.h = __float2bfloat16(x);   // RNE; compiler pk-fuses into v_cvt_pk_bf16_f32
  return u.s;
}

__global__ __launch_bounds__(256) void prep_w_kernel(
    const float* __restrict__ mat1, const float* __restrict__ Alpha,
    const int* __restrict__ use_alpha, short* __restrict__ Aprep) {
  int t = blockIdx.x * 256 + threadIdx.x;   // o = t&255, c = t>>8
  int o = t & 255;
  int c = t >> 8;
  int ua = use_alpha[0];
  const float* src = mat1 + ((size_t)o * C_IN + c) * 8;
  short8 v;
#pragma unroll
  for (int r = 0; r < 8; ++r) {
    float s = ua ? Alpha[r] : 1.0f;
    v[r] = f2bf(src[r] * s);
  }
  // layout: slot (c*256 + o) holds 8 bf16 (r fastest)
  *(short8*)(Aprep + ((size_t)c * 256 + o) * 8) = v;
}

__global__ __launch_bounds__(512, 4) void gemm_deform_kernel(
    const float* __restrict__ mat0, const short* __restrict__ Aprep,
    const float* __restrict__ mask, float* __restrict__ out) {
  int bid = blockIdx.x;
  int wg = (bid & 7) * 64 + (bid >> 3);   // XCD swizzle (512%8==0, bijective)
  int tile_m = wg & 1;                    // M fastest: pair shares mat0 cols
  int tile_n = wg >> 1;                   // 0..255
  int o0 = tile_m * 128;
  int n0 = tile_n * 128;
  int b  = n0 >> 12;
  int p0 = n0 & 4095;

  int t    = threadIdx.x;
  int lane = t & 63;
  int w    = t >> 6;        // 0..7
  int wc   = w & 3;         // 4 column groups of 32
  int wr   = w >> 2;        // 2 row groups of 64
  int l31  = lane & 31;
  int cr   = lane >> 5;     // c-plane parity within MFMA K=16

  int col = p0 + wc * 32 + l31;
  float mk[8];
#pragma unroll
  for (int r = 0; r < 8; ++r) mk[r] = mask[r * HW_ + col];

  // A slot = c*256 + o; c = rd*8 + kq*2 + cr; o = o0 + wr*64 + mi*32 + l31
  const short8* __restrict__ Ap = (const short8*)Aprep;
  int aoff = cr * 256 + o0 + wr * 64 + l31;

  // mat0 scalar source: plane c = rd*8 + kq*2 + cr, column col
  const float* __restrict__ m0b =
      mat0 + ((size_t)b * C_IN + cr) * HW_ + col;

  f32x16 acc[2];
#pragma unroll
  for (int mi = 0; mi < 2; ++mi)
#pragma unroll
    for (int j = 0; j < 16; ++j) acc[mi][j] = 0.f;

  short8 af[4][2];                 // [kq][mi], in-place reload each phase
  float  P0[4], P1[4], P2[4], P3[4];  // P ring: residue classes rd%4

  // ---- prologue: af for round 0; P for rounds 0..3 ----
#pragma unroll
  for (int kq = 0; kq < 4; ++kq) {
#pragma unroll
    for (int mi = 0; mi < 2; ++mi)
      af[kq][mi] = Ap[aoff + kq * 512 + mi * 32];
    P0[kq] = m0b[(size_t)(0 * 8 + kq * 2) * HW_];
    P1[kq] = m0b[(size_t)(1 * 8 + kq * 2) * HW_];
    P2[kq] = m0b[(size_t)(2 * 8 + kq * 2) * HW_];
    P3[kq] = m0b[(size_t)(3 * 8 + kq * 2) * HW_];
  }

  // per-round body: compute round rd from P, reload af for rd+1,
  // refill P for rd+4 (clamped; clamped refills are never consumed)
  auto BODY = [&](int rd, float (&P)[4]) {
    int ra = rd + 1 > 31 ? 31 : rd + 1;
    int abase = ra * 2048 + aoff;
    int rp = rd + 4 > 31 ? 31 : rd + 4;
    const float* mnext = m0b + (size_t)(rp * 8) * HW_;
#pragma unroll
    for (int kq = 0; kq < 4; ++kq) {
      short8 bv;
#pragma unroll
      for (int r = 0; r < 8; ++r) bv[r] = f2bf(P[kq] * mk[r]);
      acc[0] = __builtin_amdgcn_mfma_f32_32x32x16_bf16(af[kq][0], bv, acc[0], 0, 0, 0);
      acc[1] = __builtin_amdgcn_mfma_f32_32x32x16_bf16(af[kq][1], bv, acc[1], 0, 0, 0);
      af[kq][0] = Ap[abase + kq * 512];        // for round rd+1 (L2, 3-phase cover)
      af[kq][1] = Ap[abase + kq * 512 + 32];
      P[kq] = mnext[(size_t)(kq * 2) * HW_];   // for round rd+4 (HBM/L3, 4-round cover)
    }
  };

  // ---- main loop: zero barriers, unrolled x4 for static ring indices ----
#pragma unroll 1
  for (int rd = 0; rd < NRND; rd += 4) {
    BODY(rd + 0, P0);
    BODY(rd + 1, P1);
    BODY(rd + 2, P2);
    BODY(rd + 3, P3);
  }

  // ---- epilogue: 32x32 C/D layout col=lane&31, row=(reg&3)+8*(reg>>2)+4*cr ----
  size_t obase = (size_t)b * 256 * HW_ + col;
#pragma unroll
  for (int mi = 0; mi < 2; ++mi) {
#pragma unroll
    for (int reg = 0; reg < 16; ++reg) {
      int row = o0 + wr * 64 + mi * 32 + (reg & 3) + 8 * (reg >> 2) + 4 * cr;
      out[obase + (size_t)row * HW_] = acc[mi][reg];
    }
  }
}

extern "C" void kernel_launch(void* const* d_in, const int* in_sizes, int n_in,
                              void* d_out, int out_size, void* d_ws, size_t ws_size,
                              hipStream_t stream) {
  const float* mat0      = (const float*)d_in[0];   // [8,256,64,64]
  const float* mat1      = (const float*)d_in[1];   // [256,256,8]
  const float* mask      = (const float*)d_in[2];   // [8,64,64]
  const float* Alpha     = (const float*)d_in[3];   // [8]
  const int*   use_alpha = (const int*)d_in[4];     // [1]
  (void)in_sizes; (void)n_in; (void)out_size; (void)ws_size;

  short* Aprep = (short*)d_ws;                      // 1 MiB scratch
  float* outp  = (float*)d_out;

  prep_w_kernel<<<256, 256, 0, stream>>>(mat1, Alpha, use_alpha, Aprep);
  gemm_deform_kernel<<<512, 512, 0, stream>>>(mat0, Aprep, mask, outp);
}

// Round 8
// 53.304 us; speedup vs baseline: 1.1196x; 1.1196x over previous
//
#include <hip/hip_runtime.h>
#include <hip/hip_bf16.h>
#include <stdint.h>

// out[b,o,p] = sum_{r,c} mat0[b,c,p] * mat1[o,c,r]*Alpha[r] * mask[r,p]
// GEMM: M=256 (o), N=32768 (n=b*4096+p), K=2048 (k=c*8+r).
// A[o,k] = mat1[o,c,r]*Alpha[r]  (prepped bf16 in d_ws, layout [c][o][8r])
// B[k,n] = mat0[b,c,p]*mask[r,p] synthesized IN REGISTERS per lane.
// Round 8: R3/R6/R7 were VMEM-path bound (~20-32 B/cyc/CU serving redundant
// A-fragment loads). Fix: A staged to LDS once per block-round via
// global_load_lds (16 KB slab, double-buffered), fragments via ds_read_b128
// (128 B/cyc pipe). Wave tile 64x64 (4 waves = 2x2 per 128x128 block) halves
// operand-fill per MFMA. B-synth stays in registers. One barrier per round.

typedef __attribute__((ext_vector_type(8)))  short short8;
typedef __attribute__((ext_vector_type(16))) float f32x16;

#define C_IN  256
#define HW_   4096
#define NRND  32    // K rounds of 64 (8 c-planes per round)

__device__ __forceinline__ short f2bf(float x) {
  union { __hip_bfloat16 h; short s; } u;
  u.h = __float2bfloat16(x);   // RNE; compiler pk-fuses into v_cvt_pk_bf16_f32
  return u.s;
}

__global__ __launch_bounds__(256) void prep_w_kernel(
    const float* __restrict__ mat1, const float* __restrict__ Alpha,
    const int* __restrict__ use_alpha, short* __restrict__ Aprep) {
  int t = blockIdx.x * 256 + threadIdx.x;   // o = t&255, c = t>>8
  int o = t & 255;
  int c = t >> 8;
  int ua = use_alpha[0];
  const float* src = mat1 + ((size_t)o * C_IN + c) * 8;
  short8 v;
#pragma unroll
  for (int r = 0; r < 8; ++r) {
    float s = ua ? Alpha[r] : 1.0f;
    v[r] = f2bf(src[r] * s);
  }
  // layout: slot (c*256 + o) holds 8 bf16 (r fastest)
  *(short8*)(Aprep + ((size_t)c * 256 + o) * 8) = v;
}

__global__ __launch_bounds__(256, 2) void gemm_deform_kernel(
    const float* __restrict__ mat0, const short* __restrict__ Aprep,
    const float* __restrict__ mask, float* __restrict__ out) {
  // A slab per round: 8 c-planes x 128 rows, slot = cq*128 + (o-o0), 16B slots
  __shared__ short8 A_lds[2][1024];   // 2 x 16 KiB double buffer

  int bid = blockIdx.x;
  int wg = (bid & 7) * 64 + (bid >> 3);   // XCD swizzle (512%8==0, bijective)
  int tile_m = wg & 1;                    // M fastest: pair shares mat0 cols
  int tile_n = wg >> 1;                   // 0..255
  int o0 = tile_m * 128;
  int n0 = tile_n * 128;
  int b  = n0 >> 12;
  int p0 = n0 & 4095;

  int t    = threadIdx.x;
  int lane = t & 63;
  int w    = t >> 6;        // 0..3
  int wc   = w & 1;         // N-half (64 cols)
  int wr   = w >> 1;        // M-half (64 rows)
  int l31  = lane & 31;
  int cr   = lane >> 5;     // c-plane parity within MFMA K=16

  // this wave's two 32-col groups; lane-resident mask values
  int colb = p0 + wc * 64 + l31;
  float mk[2][8];
#pragma unroll
  for (int ni = 0; ni < 2; ++ni)
#pragma unroll
    for (int r = 0; r < 8; ++r)
      mk[ni][r] = mask[r * HW_ + colb + ni * 32];

  // mat0 scalar source: plane c = rd*8 + kq*2 + cr, columns colb, colb+32
  const float* __restrict__ m0b =
      mat0 + ((size_t)b * C_IN + cr) * HW_ + colb;

  // A staging: global slot (16B units) in Aprep; LDS dest wave-uniform base
  const __attribute__((address_space(1))) uint32_t* gA =
      (const __attribute__((address_space(1))) uint32_t*)Aprep;
  int soo  = (w & 1) * 64 + lane;   // column part of this thread's src slot
  int scqb = w >> 1;                // c-plane parity of this thread's src slot

  f32x16 acc[2][2];   // [mi][ni]
#pragma unroll
  for (int mi = 0; mi < 2; ++mi)
#pragma unroll
    for (int ni = 0; ni < 2; ++ni)
#pragma unroll
      for (int j = 0; j < 16; ++j) acc[mi][ni][j] = 0.f;

  float P0[4][2], P1[4][2];   // [kq][ni] mat0 scalars, ping-pong by round parity

  auto STAGE = [&](int rd, int buf) {
    __attribute__((address_space(3))) uint32_t* lA =
        (__attribute__((address_space(3))) uint32_t*)&A_lds[buf][0];
#pragma unroll
    for (int i = 0; i < 4; ++i) {
      // dest slot block i*256 + w*64 (+lane by HW); src slot matches linearly
      int gslot = (rd * 8 + i * 2 + scqb) * 256 + o0 + soo;
      __builtin_amdgcn_global_load_lds(gA + (size_t)gslot * 4,
                                       lA + (size_t)(i * 256 + w * 64) * 4,
                                       16, 0, 0);
    }
  };

  auto LOADP = [&](float (&P)[4][2], int rd) {
    const float* mp = m0b + (size_t)(rd * 8) * HW_;
#pragma unroll
    for (int kq = 0; kq < 4; ++kq) {
      P[kq][0] = mp[(size_t)(kq * 2) * HW_];
      P[kq][1] = mp[(size_t)(kq * 2) * HW_ + 32];
    }
  };

  // compute round rd from A_lds[buf] + P; refill P for round rd+2 (clamped)
  auto COMP = [&](const short8* __restrict__ Abuf, float (&P)[4][2], int rd) {
    int rp = rd + 2 > 31 ? 31 : rd + 2;
    const float* mnext = m0b + (size_t)(rp * 8) * HW_;
#pragma unroll
    for (int kq = 0; kq < 4; ++kq) {
      short8 a0 = Abuf[(kq * 2 + cr) * 128 + wr * 64 + l31];
      short8 a1 = Abuf[(kq * 2 + cr) * 128 + wr * 64 + 32 + l31];
      short8 bv0, bv1;
#pragma unroll
      for (int r = 0; r < 8; ++r) {
        bv0[r] = f2bf(P[kq][0] * mk[0][r]);
        bv1[r] = f2bf(P[kq][1] * mk[1][r]);
      }
      acc[0][0] = __builtin_amdgcn_mfma_f32_32x32x16_bf16(a0, bv0, acc[0][0], 0, 0, 0);
      acc[0][1] = __builtin_amdgcn_mfma_f32_32x32x16_bf16(a0, bv1, acc[0][1], 0, 0, 0);
      acc[1][0] = __builtin_amdgcn_mfma_f32_32x32x16_bf16(a1, bv0, acc[1][0], 0, 0, 0);
      acc[1][1] = __builtin_amdgcn_mfma_f32_32x32x16_bf16(a1, bv1, acc[1][1], 0, 0, 0);
      // refill this kq's P for round rd+2 (issued mid-round; L2/L3-resident)
      P[kq][0] = mnext[(size_t)(kq * 2) * HW_];
      P[kq][1] = mnext[(size_t)(kq * 2) * HW_ + 32];
    }
  };

  // ---- prologue ----
  STAGE(0, 0);
  LOADP(P0, 0);
  LOADP(P1, 1);
  __syncthreads();   // A(0) resident

  // ---- main loop: 2 rounds per iter, static buffer indices ----
#pragma unroll 1
  for (int rd = 0; rd < NRND; rd += 2) {
    STAGE(rd + 1, 1);                      // A(rd+1) in flight across COMP
    COMP(&A_lds[0][0], P0, rd);
    __syncthreads();                       // drains stage(rd+1); buf0 free
    if (rd + 2 < NRND) STAGE(rd + 2, 0);
    COMP(&A_lds[1][0], P1, rd + 1);
    __syncthreads();                       // drains stage(rd+2); buf1 free
  }

  // ---- epilogue: 32x32 C/D layout col=lane&31, row=(reg&3)+8*(reg>>2)+4*cr ----
  size_t obase = (size_t)b * 256 * HW_ + colb;
#pragma unroll
  for (int mi = 0; mi < 2; ++mi) {
#pragma unroll
    for (int ni = 0; ni < 2; ++ni) {
#pragma unroll
      for (int reg = 0; reg < 16; ++reg) {
        int row = o0 + wr * 64 + mi * 32 + (reg & 3) + 8 * (reg >> 2) + 4 * cr;
        out[obase + (size_t)row * HW_ + ni * 32] = acc[mi][ni][reg];
      }
    }
  }
}

extern "C" void kernel_launch(void* const* d_in, const int* in_sizes, int n_in,
                              void* d_out, int out_size, void* d_ws, size_t ws_size,
                              hipStream_t stream) {
  const float* mat0      = (const float*)d_in[0];   // [8,256,64,64]
  const float* mat1      = (const float*)d_in[1];   // [256,256,8]
  const float* mask      = (const float*)d_in[2];   // [8,64,64]
  const float* Alpha     = (const float*)d_in[3];   // [8]
  const int*   use_alpha = (const int*)d_in[4];     // [1]
  (void)in_sizes; (void)n_in; (void)out_size; (void)ws_size;

  short* Aprep = (short*)d_ws;                      // 1 MiB scratch
  float* outp  = (float*)d_out;

  prep_w_kernel<<<256, 256, 0, stream>>>(mat1, Alpha, use_alpha, Aprep);
  gemm_deform_kernel<<<512, 256, 0, stream>>>(mat0, Aprep, mask, outp);
}

// Round 9
// 48.133 us; speedup vs baseline: 1.2398x; 1.1074x over previous
//
#include <hip/hip_runtime.h>
#include <hip/hip_bf16.h>
#include <stdint.h>

// out[b,o,p] = sum_{r,c} mat0[b,c,p] * mat1[o,c,r]*Alpha[r] * mask[r,p]
// GEMM: M=256 (o), N=32768 (n=b*4096+p), K=2048 (k=c*8+r).
// A[o,k] = mat1[o,c,r]*Alpha[r]  (prepped FP16 in d_ws, layout [c][o][8r])
// B[k,n] = mat0[b,c,p]*mask[r,p] synthesized IN REGISTERS per lane (fp16).
// Round 9 = R8 geometry + two levers:
//  (1) fp16 path: synth = 1 v_cvt_f16_f32 + 4 v_pk_mul_f16 per 8 vals
//      (was ~32 scalar ops); mfma_f32_32x32x16_f16. VALU 41K->~18K cyc/CU.
//  (2) T4 counted vmcnt: raw s_barrier + s_waitcnt vmcnt(8) — never drain
//      to 0 in the main loop (P-refills stay in flight across barriers).

typedef __attribute__((ext_vector_type(8)))  _Float16 half8;
typedef __attribute__((ext_vector_type(16))) float    f32x16;

#define C_IN  256
#define HW_   4096
#define NRND  32    // K rounds of 64 (8 c-planes per round)

__global__ __launch_bounds__(256) void prep_w_kernel(
    const float* __restrict__ mat1, const float* __restrict__ Alpha,
    const int* __restrict__ use_alpha, _Float16* __restrict__ Aprep) {
  int t = blockIdx.x * 256 + threadIdx.x;   // o = t&255, c = t>>8
  int o = t & 255;
  int c = t >> 8;
  int ua = use_alpha[0];
  const float* src = mat1 + ((size_t)o * C_IN + c) * 8;
  half8 v;
#pragma unroll
  for (int r = 0; r < 8; ++r) {
    float s = ua ? Alpha[r] : 1.0f;
    v[r] = (_Float16)(src[r] * s);
  }
  // layout: slot (c*256 + o) holds 8 fp16 (r fastest)
  *(half8*)(Aprep + ((size_t)c * 256 + o) * 8) = v;
}

__global__ __launch_bounds__(256, 2) void gemm_deform_kernel(
    const float* __restrict__ mat0, const _Float16* __restrict__ Aprep,
    const float* __restrict__ mask, float* __restrict__ out) {
  // A slab per round: 8 c-planes x 128 rows, slot = cq*128 + (o-o0), 16B slots
  __shared__ half8 A_lds[2][1024];   // 2 x 16 KiB double buffer

  int bid = blockIdx.x;
  int wg = (bid & 7) * 64 + (bid >> 3);   // XCD swizzle (512%8==0, bijective)
  int tile_m = wg & 1;                    // M fastest: pair shares mat0 cols
  int tile_n = wg >> 1;                   // 0..255
  int o0 = tile_m * 128;
  int n0 = tile_n * 128;
  int b  = n0 >> 12;
  int p0 = n0 & 4095;

  int t    = threadIdx.x;
  int lane = t & 63;
  int w    = t >> 6;        // 0..3
  int wc   = w & 1;         // N-half (64 cols)
  int wr   = w >> 1;        // M-half (64 rows)
  int l31  = lane & 31;
  int cr   = lane >> 5;     // c-plane parity within MFMA K=16

  // this wave's two 32-col groups; lane-resident mask values as packed fp16
  int colb = p0 + wc * 64 + l31;
  half8 mkh[2];
#pragma unroll
  for (int ni = 0; ni < 2; ++ni)
#pragma unroll
    for (int r = 0; r < 8; ++r)
      mkh[ni][r] = (_Float16)mask[r * HW_ + colb + ni * 32];

  // mat0 scalar source: plane c = rd*8 + kq*2 + cr, columns colb, colb+32
  const float* __restrict__ m0b =
      mat0 + ((size_t)b * C_IN + cr) * HW_ + colb;

  // A staging: global slot (16B units) in Aprep; LDS dest wave-uniform base
  const __attribute__((address_space(1))) uint32_t* gA =
      (const __attribute__((address_space(1))) uint32_t*)Aprep;
  int soo  = (w & 1) * 64 + lane;   // column part of this thread's src slot
  int scqb = w >> 1;                // c-plane parity of this thread's src slot

  f32x16 acc[2][2];   // [mi][ni]
#pragma unroll
  for (int mi = 0; mi < 2; ++mi)
#pragma unroll
    for (int ni = 0; ni < 2; ++ni)
#pragma unroll
      for (int j = 0; j < 16; ++j) acc[mi][ni][j] = 0.f;

  float P0[4][2], P1[4][2];   // [kq][ni] mat0 scalars, ping-pong by parity

  auto STAGE = [&](int rd, int buf) {   // 4 global_load_lds (vmcnt +4)
    __attribute__((address_space(3))) uint32_t* lA =
        (__attribute__((address_space(3))) uint32_t*)&A_lds[buf][0];
#pragma unroll
    for (int i = 0; i < 4; ++i) {
      int gslot = (rd * 8 + i * 2 + scqb) * 256 + o0 + soo;
      __builtin_amdgcn_global_load_lds(gA + (size_t)gslot * 4,
                                       lA + (size_t)(i * 256 + w * 64) * 4,
                                       16, 0, 0);
    }
  };

  auto LOADP = [&](float (&P)[4][2], int rd) {   // 8 loads (vmcnt +8)
    const float* mp = m0b + (size_t)(rd * 8) * HW_;
#pragma unroll
    for (int kq = 0; kq < 4; ++kq) {
      P[kq][0] = mp[(size_t)(kq * 2) * HW_];
      P[kq][1] = mp[(size_t)(kq * 2) * HW_ + 32];
    }
  };

  // compute round rd from A_lds[buf] + P; refill P for round rd+2 (clamped)
  auto COMP = [&](const half8* __restrict__ Abuf, float (&P)[4][2], int rd) {
    int rp = rd + 2 > 31 ? 31 : rd + 2;
    const float* mnext = m0b + (size_t)(rp * 8) * HW_;
#pragma unroll
    for (int kq = 0; kq < 4; ++kq) {
      half8 a0 = Abuf[(kq * 2 + cr) * 128 + wr * 64 + l31];
      half8 a1 = Abuf[(kq * 2 + cr) * 128 + wr * 64 + 32 + l31];
      _Float16 h0 = (_Float16)P[kq][0];
      _Float16 h1 = (_Float16)P[kq][1];
      half8 pb0 = {h0, h0, h0, h0, h0, h0, h0, h0};
      half8 pb1 = {h1, h1, h1, h1, h1, h1, h1, h1};
      half8 bv0 = pb0 * mkh[0];   // 4x v_pk_mul_f16
      half8 bv1 = pb1 * mkh[1];
      acc[0][0] = __builtin_amdgcn_mfma_f32_32x32x16_f16(a0, bv0, acc[0][0], 0, 0, 0);
      acc[0][1] = __builtin_amdgcn_mfma_f32_32x32x16_f16(a0, bv1, acc[0][1], 0, 0, 0);
      acc[1][0] = __builtin_amdgcn_mfma_f32_32x32x16_f16(a1, bv0, acc[1][0], 0, 0, 0);
      acc[1][1] = __builtin_amdgcn_mfma_f32_32x32x16_f16(a1, bv1, acc[1][1], 0, 0, 0);
      // refill this kq's P for round rd+2 (stays in flight across barriers)
      P[kq][0] = mnext[(size_t)(kq * 2) * HW_];
      P[kq][1] = mnext[(size_t)(kq * 2) * HW_ + 32];
    }
  };

  // ---- prologue ----
  STAGE(0, 0);       // 4 outstanding
  LOADP(P0, 0);      // +8
  LOADP(P1, 1);      // +8 -> 20
  asm volatile("s_waitcnt vmcnt(16)" ::: "memory");   // stage(0) landed
  __builtin_amdgcn_s_barrier();

  // ---- main loop: counted vmcnt, never 0 ----
#pragma unroll 1
  for (int rd = 0; rd < NRND; rd += 2) {
    STAGE(rd + 1, 1);                      // +4
    COMP(&A_lds[0][0], P0, rd);            // +8 (P0 refill)
    asm volatile("s_waitcnt vmcnt(8)" ::: "memory");  // stage(rd+1) landed
    __builtin_amdgcn_s_barrier();          // buf0 free, buf1 ready
    if (rd + 2 < NRND) STAGE(rd + 2, 0);   // +4
    COMP(&A_lds[1][0], P1, rd + 1);        // +8 (P1 refill)
    asm volatile("s_waitcnt vmcnt(8)" ::: "memory");  // stage(rd+2) landed
    __builtin_amdgcn_s_barrier();          // buf1 free, buf0 ready
  }

  // ---- epilogue: 32x32 C/D layout col=lane&31, row=(reg&3)+8*(reg>>2)+4*cr ----
  size_t obase = (size_t)b * 256 * HW_ + colb;
#pragma unroll
  for (int mi = 0; mi < 2; ++mi) {
#pragma unroll
    for (int ni = 0; ni < 2; ++ni) {
#pragma unroll
      for (int reg = 0; reg < 16; ++reg) {
        int row = o0 + wr * 64 + mi * 32 + (reg & 3) + 8 * (reg >> 2) + 4 * cr;
        out[obase + (size_t)row * HW_ + ni * 32] = acc[mi][ni][reg];
      }
    }
  }
}

extern "C" void kernel_launch(void* const* d_in, const int* in_sizes, int n_in,
                              void* d_out, int out_size, void* d_ws, size_t ws_size,
                              hipStream_t stream) {
  const float* mat0      = (const float*)d_in[0];   // [8,256,64,64]
  const float* mat1      = (const float*)d_in[1];   // [256,256,8]
  const float* mask      = (const float*)d_in[2];   // [8,64,64]
  const float* Alpha     = (const float*)d_in[3];   // [8]
  const int*   use_alpha = (const int*)d_in[4];     // [1]
  (void)in_sizes; (void)n_in; (void)out_size; (void)ws_size;

  _Float16* Aprep = (_Float16*)d_ws;                // 1 MiB scratch
  float* outp  = (float*)d_out;

  prep_w_kernel<<<256, 256, 0, stream>>>(mat1, Alpha, use_alpha, Aprep);
  gemm_deform_kernel<<<512, 256, 0, stream>>>(mat0, Aprep, mask, outp);
}